// Round 1
// baseline (2240.494 us; speedup 1.0000x reference)
//
#include <hip/hip_runtime.h>
#include <hip/hip_bf16.h>
#include <math.h>

// Problem constants (from reference):
#define B 16
#define T 2048
#define D 1024
#define H 128
#define SCALE 0.08838834764831845f  // H^-0.5 = 1/sqrt(128)

// ---------------------------------------------------------------------------
// Kernel A: QKV projection.  y = x @ W + b  for each of (q,k,v).
// grid: (B*T/64, 3), block 256.  Each block: 64 rows x 128 cols of one output.
// Classic LDS-tiled fp32 GEMM, K-chunks of 32, 4x8 register tile per thread.
// ---------------------------------------------------------------------------
__global__ __launch_bounds__(256) void qkv_kernel(
    const float* __restrict__ x,
    const float* __restrict__ Wq, const float* __restrict__ bq,
    const float* __restrict__ Wk, const float* __restrict__ bk,
    const float* __restrict__ Wv, const float* __restrict__ bv,
    float* __restrict__ qb, float* __restrict__ kb, float* __restrict__ vb)
{
    const int tid = threadIdx.x;
    const int row0 = blockIdx.x * 64;

    const float* W; const float* bias; float* out;
    if (blockIdx.y == 0)      { W = Wq; bias = bq; out = qb; }
    else if (blockIdx.y == 1) { W = Wk; bias = bk; out = kb; }
    else                      { W = Wv; bias = bv; out = vb; }

    __shared__ float xs[32][68];   // [kk][row] (transposed), padded
    __shared__ float wsm[32][132]; // [kk][col], padded

    const int ty = tid >> 4;   // 0..15 -> row group (4 rows)
    const int tx = tid & 15;   // 0..15 -> col group (8 cols)

    float acc[4][8];
    #pragma unroll
    for (int r = 0; r < 4; ++r)
        #pragma unroll
        for (int c = 0; c < 8; ++c) acc[r][c] = 0.f;

    for (int k0 = 0; k0 < D; k0 += 32) {
        // stage x tile (64 rows x 32 k), transposed into xs[kk][row]
        #pragma unroll
        for (int i = 0; i < 2; ++i) {
            int idx = tid + i * 256;        // 0..511 float4s
            int r   = idx >> 3;             // row 0..63
            int c4  = idx & 7;              // float4 col 0..7
            float4 v4 = *(const float4*)(x + (size_t)(row0 + r) * D + k0 + c4 * 4);
            xs[c4 * 4 + 0][r] = v4.x;
            xs[c4 * 4 + 1][r] = v4.y;
            xs[c4 * 4 + 2][r] = v4.z;
            xs[c4 * 4 + 3][r] = v4.w;
        }
        // stage W tile (32 k x 128 cols)
        #pragma unroll
        for (int i = 0; i < 4; ++i) {
            int idx = tid + i * 256;        // 0..1023 float4s
            int r   = idx >> 5;             // k 0..31
            int c4  = idx & 31;             // float4 col 0..31
            *(float4*)(&wsm[r][c4 * 4]) =
                *(const float4*)(W + (size_t)(k0 + r) * H + c4 * 4);
        }
        __syncthreads();

        #pragma unroll
        for (int kk = 0; kk < 32; ++kk) {
            float4 a  = *(const float4*)(&xs[kk][ty * 4]);
            float4 b0 = *(const float4*)(&wsm[kk][tx * 8]);
            float4 b1 = *(const float4*)(&wsm[kk][tx * 8 + 4]);
            float av[4]  = {a.x, a.y, a.z, a.w};
            float bv8[8] = {b0.x, b0.y, b0.z, b0.w, b1.x, b1.y, b1.z, b1.w};
            #pragma unroll
            for (int r = 0; r < 4; ++r)
                #pragma unroll
                for (int c = 0; c < 8; ++c)
                    acc[r][c] = fmaf(av[r], bv8[c], acc[r][c]);
        }
        __syncthreads();
    }

    #pragma unroll
    for (int r = 0; r < 4; ++r) {
        int row = row0 + ty * 4 + r;
        #pragma unroll
        for (int c2 = 0; c2 < 2; ++c2) {
            int col = tx * 8 + c2 * 4;
            float4 o;
            o.x = acc[r][c2 * 4 + 0] + bias[col + 0];
            o.y = acc[r][c2 * 4 + 1] + bias[col + 1];
            o.z = acc[r][c2 * 4 + 2] + bias[col + 2];
            o.w = acc[r][c2 * 4 + 3] + bias[col + 3];
            *(float4*)(out + (size_t)row * H + col) = o;
        }
    }
}

// ---------------------------------------------------------------------------
// Kernel B: per-COLUMN softmax stats (reference softmax is over axis=1!).
// For column j: m = max_{i>=j} s[i][j], sum = sum exp(s-m); store m and 1/sum.
// grid: (T/64, B), block 256. Thread (jl,g): column j = j0+jl, d-chunk g*32.
// k[j] fragment register-resident; q rows staged to LDS, broadcast-read.
// ---------------------------------------------------------------------------
__global__ __launch_bounds__(256) void colstats_kernel(
    const float* __restrict__ qb, const float* __restrict__ kb,
    float* __restrict__ cmax, float* __restrict__ cinv)
{
    const int tid = threadIdx.x;
    const int bb  = blockIdx.y;
    const int j0  = blockIdx.x * 64;
    const int jl  = tid >> 2;   // 0..63
    const int g   = tid & 3;    // 0..3
    const int j   = j0 + jl;

    const float* qB = qb + (size_t)bb * T * H;
    const float* kB = kb + (size_t)bb * T * H;

    float kf[32];
    #pragma unroll
    for (int i = 0; i < 8; ++i) {
        float4 v4 = *(const float4*)(kB + (size_t)j * H + g * 32 + i * 4);
        kf[i * 4 + 0] = v4.x; kf[i * 4 + 1] = v4.y;
        kf[i * 4 + 2] = v4.z; kf[i * 4 + 3] = v4.w;
    }

    __shared__ float qs[8][132];

    float m = -INFINITY, s = 0.f;

    for (int i0 = j0; i0 < T; i0 += 8) {
        {   // stage 8 q rows (256 float4s, one per thread)
            int r  = tid >> 5;          // 0..7
            int c4 = tid & 31;          // 0..31
            *(float4*)(&qs[r][c4 * 4]) =
                *(const float4*)(qB + (size_t)(i0 + r) * H + c4 * 4);
        }
        __syncthreads();
        #pragma unroll
        for (int il = 0; il < 8; ++il) {
            int i = i0 + il;
            float dot = 0.f;
            #pragma unroll
            for (int d = 0; d < 8; ++d) {
                float4 v4 = *(const float4*)(&qs[il][g * 32 + d * 4]);
                dot = fmaf(v4.x, kf[d * 4 + 0], dot);
                dot = fmaf(v4.y, kf[d * 4 + 1], dot);
                dot = fmaf(v4.z, kf[d * 4 + 2], dot);
                dot = fmaf(v4.w, kf[d * 4 + 3], dot);
            }
            dot += __shfl_xor(dot, 1, 4);
            dot += __shfl_xor(dot, 2, 4);
            if (i >= j) {
                float val = dot * SCALE;
                float nm  = fmaxf(m, val);
                s = s * __expf(m - nm) + __expf(val - nm);
                m = nm;
            }
        }
        __syncthreads();
    }
    if (g == 0) {
        cmax[(size_t)bb * T + j] = m;
        cinv[(size_t)bb * T + j] = 1.0f / s;
    }
}

// ---------------------------------------------------------------------------
// Kernel C: output.  out[q] = sum_{j<=q} exp(s[q][j]-cmax[j])*cinv[j] * v[j].
// grid: (T/64, B), block 256. Thread (ql,g): q row q0+ql, h-chunk g*32.
// q fragment register-resident; k/v rows + stats staged per 8-j chunk.
// ---------------------------------------------------------------------------
__global__ __launch_bounds__(256) void out_kernel(
    const float* __restrict__ qb, const float* __restrict__ kb,
    const float* __restrict__ vb,
    const float* __restrict__ cmax, const float* __restrict__ cinv,
    float* __restrict__ out)
{
    const int tid = threadIdx.x;
    const int bb  = blockIdx.y;
    const int q0  = blockIdx.x * 64;
    const int ql  = tid >> 2;
    const int g   = tid & 3;
    const int q   = q0 + ql;

    const float* qB = qb + (size_t)bb * T * H;
    const float* kB = kb + (size_t)bb * T * H;
    const float* vB = vb + (size_t)bb * T * H;

    float qf[32];
    #pragma unroll
    for (int i = 0; i < 8; ++i) {
        float4 v4 = *(const float4*)(qB + (size_t)q * H + g * 32 + i * 4);
        qf[i * 4 + 0] = v4.x; qf[i * 4 + 1] = v4.y;
        qf[i * 4 + 2] = v4.z; qf[i * 4 + 3] = v4.w;
    }

    float acc[32];
    #pragma unroll
    for (int i = 0; i < 32; ++i) acc[i] = 0.f;

    __shared__ float ks[8][132];
    __shared__ float vs[8][132];
    __shared__ float sm0[8];
    __shared__ float sm1[8];

    const int jend = q0 + 64;   // exclusive upper bound on j (j <= q < q0+64)
    for (int j0b = 0; j0b < jend; j0b += 8) {
        {
            int r  = tid >> 5;
            int c4 = tid & 31;
            *(float4*)(&ks[r][c4 * 4]) =
                *(const float4*)(kB + (size_t)(j0b + r) * H + c4 * 4);
            *(float4*)(&vs[r][c4 * 4]) =
                *(const float4*)(vB + (size_t)(j0b + r) * H + c4 * 4);
        }
        if (tid < 8) {
            sm0[tid] = cmax[(size_t)bb * T + j0b + tid];
            sm1[tid] = cinv[(size_t)bb * T + j0b + tid];
        }
        __syncthreads();
        #pragma unroll
        for (int jl2 = 0; jl2 < 8; ++jl2) {
            int jj = j0b + jl2;
            float dot = 0.f;
            #pragma unroll
            for (int d = 0; d < 8; ++d) {
                float4 v4 = *(const float4*)(&ks[jl2][g * 32 + d * 4]);
                dot = fmaf(v4.x, qf[d * 4 + 0], dot);
                dot = fmaf(v4.y, qf[d * 4 + 1], dot);
                dot = fmaf(v4.z, qf[d * 4 + 2], dot);
                dot = fmaf(v4.w, qf[d * 4 + 3], dot);
            }
            dot += __shfl_xor(dot, 1, 4);
            dot += __shfl_xor(dot, 2, 4);
            float p = __expf(dot * SCALE - sm0[jl2]) * sm1[jl2];
            if (jj > q) p = 0.f;
            #pragma unroll
            for (int d = 0; d < 8; ++d) {
                float4 v4 = *(const float4*)(&vs[jl2][g * 32 + d * 4]);
                acc[d * 4 + 0] = fmaf(p, v4.x, acc[d * 4 + 0]);
                acc[d * 4 + 1] = fmaf(p, v4.y, acc[d * 4 + 1]);
                acc[d * 4 + 2] = fmaf(p, v4.z, acc[d * 4 + 2]);
                acc[d * 4 + 3] = fmaf(p, v4.w, acc[d * 4 + 3]);
            }
        }
        __syncthreads();
    }

    float* oB = out + (size_t)bb * T * H;
    #pragma unroll
    for (int i = 0; i < 8; ++i) {
        float4 o = {acc[i * 4 + 0], acc[i * 4 + 1], acc[i * 4 + 2], acc[i * 4 + 3]};
        *(float4*)(oB + (size_t)q * H + g * 32 + i * 4) = o;
    }
}

// ---------------------------------------------------------------------------
extern "C" void kernel_launch(void* const* d_in, const int* in_sizes, int n_in,
                              void* d_out, int out_size, void* d_ws, size_t ws_size,
                              hipStream_t stream)
{
    // setup_inputs order: x, Wk, bk, Wq, bq, Wv, bv (all fp32)
    const float* x  = (const float*)d_in[0];
    const float* Wk = (const float*)d_in[1];
    const float* bk = (const float*)d_in[2];
    const float* Wq = (const float*)d_in[3];
    const float* bq = (const float*)d_in[4];
    const float* Wv = (const float*)d_in[5];
    const float* bv = (const float*)d_in[6];
    float* out = (float*)d_out;

    // workspace layout (floats): q | k | v | cmax | cinv   (~48.3 MB total)
    float* ws   = (float*)d_ws;
    float* qb   = ws;
    float* kb   = qb + (size_t)B * T * H;
    float* vb   = kb + (size_t)B * T * H;
    float* cmax = vb + (size_t)B * T * H;
    float* cinv = cmax + (size_t)B * T;

    dim3 gA(B * T / 64, 3);
    qkv_kernel<<<gA, 256, 0, stream>>>(x, Wq, bq, Wk, bk, Wv, bv, qb, kb, vb);

    dim3 gBC(T / 64, B);
    colstats_kernel<<<gBC, 256, 0, stream>>>(qb, kb, cmax, cinv);
    out_kernel<<<gBC, 256, 0, stream>>>(qb, kb, vb, cmax, cinv, out);
}

// Round 4
// 460.658 us; speedup vs baseline: 4.8637x; 4.8637x over previous
//
#include <hip/hip_runtime.h>
#include <hip/hip_bf16.h>
#include <math.h>

#define B 16
#define T 2048
#define D 1024
#define H 128
#define SCALE 0.08838834764831845f  // 1/sqrt(128)

typedef __attribute__((ext_vector_type(8))) short bf16x8;
typedef __attribute__((ext_vector_type(8))) unsigned short u16x8;
typedef __attribute__((ext_vector_type(4))) unsigned short u16x4;
typedef __attribute__((ext_vector_type(4))) float f32x4;

static __device__ __forceinline__ unsigned short f2bf(float f) {
    __hip_bfloat16 h = __float2bfloat16(f);
    return *reinterpret_cast<unsigned short*>(&h);
}

// ---------------------------------------------------------------------------
// K0: Wt[p][n][k] = bf16(W_p[k][n]);  p: 0=q,1=k,2=v.  grid (32,3), 256 thr.
// ---------------------------------------------------------------------------
__global__ __launch_bounds__(256) void wt_kernel(
    const float* __restrict__ Wq, const float* __restrict__ Wk,
    const float* __restrict__ Wv, unsigned short* __restrict__ Wt)
{
    const int tid = threadIdx.x;
    const int p = blockIdx.y;
    const int k0 = blockIdx.x * 32;
    const float* W = (p == 0) ? Wq : (p == 1) ? Wk : Wv;
    __shared__ float tile[32][132];
    #pragma unroll
    for (int it = 0; it < 4; ++it) {
        int idx = tid + it * 256;
        int k = idx >> 5, n4 = idx & 31;
        *(float4*)(&tile[k][n4 * 4]) = *(const float4*)(W + (size_t)(k0 + k) * H + n4 * 4);
    }
    __syncthreads();
    int n = tid >> 1, half = tid & 1;
    unsigned short* dst = Wt + (size_t)p * (H * D) + (size_t)n * D + k0 + half * 16;
    u16x8 o0, o1;
    #pragma unroll
    for (int e = 0; e < 8; ++e) o0[e] = f2bf(tile[half * 16 + e][n]);
    #pragma unroll
    for (int e = 0; e < 8; ++e) o1[e] = f2bf(tile[half * 16 + 8 + e][n]);
    *(u16x8*)dst = o0;
    *(u16x8*)(dst + 8) = o1;
}

// ---------------------------------------------------------------------------
// K1: QKV GEMM, bf16 MFMA.  grid (256,3), 256 thr. BM=BN=128, BK=64.
// Wave w (2x2): 64x64 tile, 4x4 frags of 16x16x32.
// p<2: store bf16 to Qh/Kh.  p==2: store transposed to Vt[b][h][t].
// ---------------------------------------------------------------------------
__global__ __launch_bounds__(256) void qkv_kernel(
    const float* __restrict__ x, const unsigned short* __restrict__ Wt,
    const float* __restrict__ bq, const float* __restrict__ bk,
    const float* __restrict__ bv,
    unsigned short* __restrict__ Qh, unsigned short* __restrict__ Kh,
    unsigned short* __restrict__ Vt)
{
    const int tid = threadIdx.x;
    const int p = blockIdx.y;
    const int row0 = blockIdx.x * 128;
    const int l = tid & 63, w = tid >> 6;
    const int wr = w >> 1, wc = w & 1;

    __shared__ __align__(16) unsigned short As[128 * 64];
    __shared__ __align__(16) unsigned short Bs[128 * 64];

    const unsigned short* Wp = Wt + (size_t)p * (H * D);

    f32x4 acc[4][4];
    #pragma unroll
    for (int mi = 0; mi < 4; ++mi)
        #pragma unroll
        for (int ni = 0; ni < 4; ++ni)
            #pragma unroll
            for (int r = 0; r < 4; ++r) acc[mi][ni][r] = 0.f;

    for (int k0 = 0; k0 < D; k0 += 64) {
        #pragma unroll
        for (int c = 0; c < 4; ++c) {
            int idx = tid + c * 256;
            int row = idx >> 3, seg = idx & 7;
            const float* src = x + (size_t)(row0 + row) * D + k0 + seg * 8;
            float4 f0 = *(const float4*)src;
            float4 f1 = *(const float4*)(src + 4);
            u16x8 u;
            u[0] = f2bf(f0.x); u[1] = f2bf(f0.y); u[2] = f2bf(f0.z); u[3] = f2bf(f0.w);
            u[4] = f2bf(f1.x); u[5] = f2bf(f1.y); u[6] = f2bf(f1.z); u[7] = f2bf(f1.w);
            *(u16x8*)(As + row * 64 + seg * 8) = u;
            *(u16x8*)(Bs + row * 64 + seg * 8) =
                *(const u16x8*)(Wp + (size_t)row * D + k0 + seg * 8);
        }
        __syncthreads();
        #pragma unroll
        for (int ks = 0; ks < 2; ++ks) {
            bf16x8 a[4], bfr[4];
            #pragma unroll
            for (int mi = 0; mi < 4; ++mi)
                a[mi] = *(const bf16x8*)(As + (wr * 64 + mi * 16 + (l & 15)) * 64 + ks * 32 + (l >> 4) * 8);
            #pragma unroll
            for (int ni = 0; ni < 4; ++ni)
                bfr[ni] = *(const bf16x8*)(Bs + (wc * 64 + ni * 16 + (l & 15)) * 64 + ks * 32 + (l >> 4) * 8);
            #pragma unroll
            for (int mi = 0; mi < 4; ++mi)
                #pragma unroll
                for (int ni = 0; ni < 4; ++ni)
                    acc[mi][ni] = __builtin_amdgcn_mfma_f32_16x16x32_bf16(a[mi], bfr[ni], acc[mi][ni], 0, 0, 0);
        }
        __syncthreads();
    }

    const float* bias = (p == 0) ? bq : (p == 1) ? bk : bv;
    if (p < 2) {
        unsigned short* O = (p == 0) ? Qh : Kh;
        #pragma unroll
        for (int ni = 0; ni < 4; ++ni) {
            int col = wc * 64 + ni * 16 + (l & 15);
            float bb = bias[col];
            #pragma unroll
            for (int mi = 0; mi < 4; ++mi) {
                int rbase = row0 + wr * 64 + mi * 16 + (l >> 4) * 4;
                #pragma unroll
                for (int r = 0; r < 4; ++r)
                    O[(size_t)(rbase + r) * H + col] = f2bf(acc[mi][ni][r] + bb);
            }
        }
    } else {
        int bidx = row0 >> 11;          // batch
        int tbase0 = row0 & (T - 1);    // token within batch
        #pragma unroll
        for (int ni = 0; ni < 4; ++ni) {
            int col = wc * 64 + ni * 16 + (l & 15);   // h
            float bb = bias[col];
            #pragma unroll
            for (int mi = 0; mi < 4; ++mi) {
                int t0 = tbase0 + wr * 64 + mi * 16 + (l >> 4) * 4;
                u16x4 u;
                #pragma unroll
                for (int r = 0; r < 4; ++r) u[r] = f2bf(acc[mi][ni][r] + bb);
                *(u16x4*)(Vt + ((size_t)bidx * H + col) * T + t0) = u;
            }
        }
    }
}

// ---------------------------------------------------------------------------
// K2: column-softmax stats (softmax over QUERY axis). grid (32,16), 256 thr.
// Block: 64 columns j; wave w owns 16 cols. K-frags register-resident;
// Q 64-row tiles staged in LDS (XOR-swizzled rows). Online (m,s) per column.
// ---------------------------------------------------------------------------
__global__ __launch_bounds__(256) void colstats_kernel(
    const unsigned short* __restrict__ Qh, const unsigned short* __restrict__ Kh,
    float* __restrict__ cmax, float* __restrict__ cinv)
{
    const int tid = threadIdx.x;
    const int b = blockIdx.y;
    const int j0 = blockIdx.x * 64;
    const int l = tid & 63, w = tid >> 6;
    const unsigned short* Qb = Qh + (size_t)b * T * H;
    const unsigned short* Kb = Kh + (size_t)b * T * H;

    const int jc = j0 + w * 16 + (l & 15);   // this lane's column

    bf16x8 kf[4];
    #pragma unroll
    for (int ks = 0; ks < 4; ++ks)
        kf[ks] = *(const bf16x8*)(Kb + (size_t)jc * H + ks * 32 + (l >> 4) * 8);

    __shared__ __align__(16) unsigned short Qs[64 * 128];
    char* qsb = (char*)Qs;

    float m = -3.0e38f, s = 0.f;

    for (int i0 = j0; i0 < T; i0 += 64) {
        #pragma unroll
        for (int c = 0; c < 4; ++c) {
            int idx = tid + c * 256;
            int row = idx >> 4, seg = idx & 15;
            u16x8 u = *(const u16x8*)(Qb + (size_t)(i0 + row) * H + seg * 8);
            *(u16x8*)(qsb + row * 256 + ((seg * 16) ^ ((row & 7) << 4))) = u;
        }
        __syncthreads();
        float mv[16];
        #pragma unroll
        for (int mi = 0; mi < 4; ++mi) {
            f32x4 Dd = {0.f, 0.f, 0.f, 0.f};
            #pragma unroll
            for (int ks = 0; ks < 4; ++ks) {
                int row = mi * 16 + (l & 15);
                bf16x8 a = *(const bf16x8*)(qsb + row * 256 +
                            ((ks * 64 + (l >> 4) * 16) ^ ((l & 7) << 4)));
                Dd = __builtin_amdgcn_mfma_f32_16x16x32_bf16(a, kf[ks], Dd, 0, 0, 0);
            }
            #pragma unroll
            for (int r = 0; r < 4; ++r) {
                int i = i0 + mi * 16 + (l >> 4) * 4 + r;
                mv[mi * 4 + r] = (i >= jc) ? Dd[r] * SCALE : -3.0e38f;
            }
        }
        float tmax = mv[0];
        #pragma unroll
        for (int e = 1; e < 16; ++e) tmax = fmaxf(tmax, mv[e]);
        tmax = fmaxf(tmax, __shfl_xor(tmax, 16));
        tmax = fmaxf(tmax, __shfl_xor(tmax, 32));
        float newm = fmaxf(m, tmax);
        float tsum = 0.f;
        #pragma unroll
        for (int e = 0; e < 16; ++e)
            tsum += (mv[e] > -1.0e37f) ? __expf(mv[e] - newm) : 0.f;
        tsum += __shfl_xor(tsum, 16);
        tsum += __shfl_xor(tsum, 32);
        s = s * __expf(m - newm) + tsum;
        m = newm;
        __syncthreads();
    }
    if (l < 16) {
        cmax[(size_t)b * T + j0 + w * 16 + l] = m;
        cinv[(size_t)b * T + j0 + w * 16 + l] = 1.0f / s;
    }
}

// ---------------------------------------------------------------------------
// K3: out[i][h] = sum_{j<=i} exp(S*scale - cmax[j])*cinv[j] * V[j][h].
// grid (32,16), 256 thr. Block: 64 i-rows; wave w: 16 i-rows, all 128 h.
// Q frags direct from global (register-resident); K/Vt tiles LDS-swizzled;
// P transposed through per-wave swizzled LDS into PV A-frags.
// ---------------------------------------------------------------------------
__global__ __launch_bounds__(256) void out_kernel(
    const unsigned short* __restrict__ Qh, const unsigned short* __restrict__ Kh,
    const unsigned short* __restrict__ Vt,
    const float* __restrict__ cmax, const float* __restrict__ cinv,
    float* __restrict__ out)
{
    const int tid = threadIdx.x;
    const int b = blockIdx.y;
    const int i0 = blockIdx.x * 64;
    const int l = tid & 63, w = tid >> 6;

    const unsigned short* Qb = Qh + (size_t)b * T * H;
    const unsigned short* Kb = Kh + (size_t)b * T * H;
    const unsigned short* Vb = Vt + (size_t)b * H * T;

    const int irow = i0 + w * 16 + (l & 15);   // A-frag row (m = i)
    bf16x8 qf[4];
    #pragma unroll
    for (int ks = 0; ks < 4; ++ks)
        qf[ks] = *(const bf16x8*)(Qb + (size_t)irow * H + ks * 32 + (l >> 4) * 8);

    const int iD = i0 + w * 16 + (l >> 4) * 4; // D-frag row base (i)

    f32x4 acc[8];
    #pragma unroll
    for (int nh = 0; nh < 8; ++nh)
        #pragma unroll
        for (int r = 0; r < 4; ++r) acc[nh][r] = 0.f;

    __shared__ __align__(16) unsigned short Ks[64 * 128];
    __shared__ __align__(16) unsigned short Vs[128 * 64];
    __shared__ __align__(16) unsigned short Ps[4 * 16 * 64];
    char* ksb = (char*)Ks;
    char* vsb = (char*)Vs;
    char* psb = (char*)(Ps + (size_t)w * 16 * 64);

    for (int j1 = 0; j1 <= i0; j1 += 64) {
        #pragma unroll
        for (int c = 0; c < 4; ++c) {         // stage K rows j1..j1+63
            int idx = tid + c * 256;
            int row = idx >> 4, seg = idx & 15;
            *(u16x8*)(ksb + row * 256 + ((seg * 16) ^ ((row & 7) << 4))) =
                *(const u16x8*)(Kb + (size_t)(j1 + row) * H + seg * 8);
        }
        #pragma unroll
        for (int c = 0; c < 4; ++c) {         // stage Vt[:, j1..j1+63]
            int idx = tid + c * 256;
            int row = idx >> 3, seg = idx & 7;
            *(u16x8*)(vsb + row * 128 + ((seg * 16) ^ ((row & 7) << 4))) =
                *(const u16x8*)(Vb + (size_t)row * T + j1 + seg * 8);
        }
        __syncthreads();

        #pragma unroll
        for (int nj = 0; nj < 4; ++nj) {
            f32x4 Dd = {0.f, 0.f, 0.f, 0.f};
            #pragma unroll
            for (int ks = 0; ks < 4; ++ks) {
                int row = nj * 16 + (l & 15);
                bf16x8 bk = *(const bf16x8*)(ksb + row * 256 +
                             ((ks * 64 + (l >> 4) * 16) ^ ((l & 7) << 4)));
                Dd = __builtin_amdgcn_mfma_f32_16x16x32_bf16(qf[ks], bk, Dd, 0, 0, 0);
            }
            int jc = j1 + nj * 16 + (l & 15);
            float cm = cmax[(size_t)b * T + jc];
            float ci = cinv[(size_t)b * T + jc];
            #pragma unroll
            for (int r = 0; r < 4; ++r) {
                int i = iD + r;
                float pv = (jc <= i) ? __expf(Dd[r] * SCALE - cm) * ci : 0.f;
                int prow = (l >> 4) * 4 + r;
                *(unsigned short*)(psb + prow * 128 +
                    (((nj * 16 + (l & 15)) * 2) ^ ((prow & 7) << 4))) = f2bf(pv);
            }
        }
        __syncthreads();   // P visible (also orders vs. wave's own reads)

        #pragma unroll
        for (int ks2 = 0; ks2 < 2; ++ks2) {
            int prow = l & 15;
            bf16x8 ap = *(const bf16x8*)(psb + prow * 128 +
                         ((ks2 * 64 + (l >> 4) * 16) ^ ((prow & 7) << 4)));
            #pragma unroll
            for (int nh = 0; nh < 8; ++nh) {
                int vrow = nh * 16 + (l & 15);
                bf16x8 bv_ = *(const bf16x8*)(vsb + vrow * 128 +
                              ((ks2 * 64 + (l >> 4) * 16) ^ ((l & 7) << 4)));
                acc[nh] = __builtin_amdgcn_mfma_f32_16x16x32_bf16(ap, bv_, acc[nh], 0, 0, 0);
            }
        }
        __syncthreads();
    }

    float* Ob = out + (size_t)b * T * H;
    #pragma unroll
    for (int nh = 0; nh < 8; ++nh) {
        int col = nh * 16 + (l & 15);
        #pragma unroll
        for (int r = 0; r < 4; ++r)
            Ob[(size_t)(iD + r) * H + col] = acc[nh][r];
    }
}

// ---------------------------------------------------------------------------
extern "C" void kernel_launch(void* const* d_in, const int* in_sizes, int n_in,
                              void* d_out, int out_size, void* d_ws, size_t ws_size,
                              hipStream_t stream)
{
    // inputs: x, Wk, bk, Wq, bq, Wv, bv (fp32)
    const float* x  = (const float*)d_in[0];
    const float* Wk = (const float*)d_in[1];
    const float* bk = (const float*)d_in[2];
    const float* Wq = (const float*)d_in[3];
    const float* bq = (const float*)d_in[4];
    const float* Wv = (const float*)d_in[5];
    const float* bv = (const float*)d_in[6];
    float* out = (float*)d_out;

    // ws layout (bytes): Qh 8M | Kh 8M | Vt 8M | Wt 768K | cmax 128K | cinv 128K
    char* ws = (char*)d_ws;
    unsigned short* Qh = (unsigned short*)(ws);
    unsigned short* Kh = (unsigned short*)(ws + 8388608);
    unsigned short* Vt = (unsigned short*)(ws + 16777216);
    unsigned short* Wt = (unsigned short*)(ws + 25165824);
    float* cmax = (float*)(ws + 25952256);
    float* cinv = (float*)(ws + 26083328);

    wt_kernel<<<dim3(32, 3), 256, 0, stream>>>(Wq, Wk, Wv, Wt);
    qkv_kernel<<<dim3(256, 3), 256, 0, stream>>>(x, Wt, bq, bk, bv, Qh, Kh, Vt);
    colstats_kernel<<<dim3(32, B), 256, 0, stream>>>(Qh, Kh, cmax, cinv);
    out_kernel<<<dim3(32, B), 256, 0, stream>>>(Qh, Kh, Vt, cmax, cinv, out);
}

// Round 5
// 350.124 us; speedup vs baseline: 6.3991x; 1.3157x over previous
//
#include <hip/hip_runtime.h>
#include <hip/hip_bf16.h>
#include <math.h>

#define B 16
#define T 2048
#define D 1024
#define H 128
#define SCALE 0.08838834764831845f  // 1/sqrt(128)

typedef __attribute__((ext_vector_type(8))) short bf16x8;
typedef __attribute__((ext_vector_type(8))) unsigned short u16x8;
typedef __attribute__((ext_vector_type(4))) unsigned short u16x4;
typedef __attribute__((ext_vector_type(4))) float f32x4;

static __device__ __forceinline__ unsigned short f2bf(float f) {
    __hip_bfloat16 h = __float2bfloat16(f);
    return *reinterpret_cast<unsigned short*>(&h);
}

// ---------------------------------------------------------------------------
// K0: Wt[p][n][k] = bf16(W_p[k][n]);  p: 0=q,1=k,2=v.  grid (32,3), 256 thr.
// (unchanged from R4 — passing baseline)
// ---------------------------------------------------------------------------
__global__ __launch_bounds__(256) void wt_kernel(
    const float* __restrict__ Wq, const float* __restrict__ Wk,
    const float* __restrict__ Wv, unsigned short* __restrict__ Wt)
{
    const int tid = threadIdx.x;
    const int p = blockIdx.y;
    const int k0 = blockIdx.x * 32;
    const float* W = (p == 0) ? Wq : (p == 1) ? Wk : Wv;
    __shared__ float tile[32][132];
    #pragma unroll
    for (int it = 0; it < 4; ++it) {
        int idx = tid + it * 256;
        int k = idx >> 5, n4 = idx & 31;
        *(float4*)(&tile[k][n4 * 4]) = *(const float4*)(W + (size_t)(k0 + k) * H + n4 * 4);
    }
    __syncthreads();
    int n = tid >> 1, half = tid & 1;
    unsigned short* dst = Wt + (size_t)p * (H * D) + (size_t)n * D + k0 + half * 16;
    u16x8 o0, o1;
    #pragma unroll
    for (int e = 0; e < 8; ++e) o0[e] = f2bf(tile[half * 16 + e][n]);
    #pragma unroll
    for (int e = 0; e < 8; ++e) o1[e] = f2bf(tile[half * 16 + 8 + e][n]);
    *(u16x8*)dst = o0;
    *(u16x8*)(dst + 8) = o1;
}

// ---------------------------------------------------------------------------
// K1: QKV GEMM (unchanged from R4 — A/B control; revisit with counters)
// ---------------------------------------------------------------------------
__global__ __launch_bounds__(256) void qkv_kernel(
    const float* __restrict__ x, const unsigned short* __restrict__ Wt,
    const float* __restrict__ bq, const float* __restrict__ bk,
    const float* __restrict__ bv,
    unsigned short* __restrict__ Qh, unsigned short* __restrict__ Kh,
    unsigned short* __restrict__ Vt)
{
    const int tid = threadIdx.x;
    const int p = blockIdx.y;
    const int row0 = blockIdx.x * 128;
    const int l = tid & 63, w = tid >> 6;
    const int wr = w >> 1, wc = w & 1;

    __shared__ __align__(16) unsigned short As[128 * 64];
    __shared__ __align__(16) unsigned short Bs[128 * 64];

    const unsigned short* Wp = Wt + (size_t)p * (H * D);

    f32x4 acc[4][4];
    #pragma unroll
    for (int mi = 0; mi < 4; ++mi)
        #pragma unroll
        for (int ni = 0; ni < 4; ++ni)
            #pragma unroll
            for (int r = 0; r < 4; ++r) acc[mi][ni][r] = 0.f;

    for (int k0 = 0; k0 < D; k0 += 64) {
        #pragma unroll
        for (int c = 0; c < 4; ++c) {
            int idx = tid + c * 256;
            int row = idx >> 3, seg = idx & 7;
            const float* src = x + (size_t)(row0 + row) * D + k0 + seg * 8;
            float4 f0 = *(const float4*)src;
            float4 f1 = *(const float4*)(src + 4);
            u16x8 u;
            u[0] = f2bf(f0.x); u[1] = f2bf(f0.y); u[2] = f2bf(f0.z); u[3] = f2bf(f0.w);
            u[4] = f2bf(f1.x); u[5] = f2bf(f1.y); u[6] = f2bf(f1.z); u[7] = f2bf(f1.w);
            *(u16x8*)(As + row * 64 + seg * 8) = u;
            *(u16x8*)(Bs + row * 64 + seg * 8) =
                *(const u16x8*)(Wp + (size_t)row * D + k0 + seg * 8);
        }
        __syncthreads();
        #pragma unroll
        for (int ks = 0; ks < 2; ++ks) {
            bf16x8 a[4], bfr[4];
            #pragma unroll
            for (int mi = 0; mi < 4; ++mi)
                a[mi] = *(const bf16x8*)(As + (wr * 64 + mi * 16 + (l & 15)) * 64 + ks * 32 + (l >> 4) * 8);
            #pragma unroll
            for (int ni = 0; ni < 4; ++ni)
                bfr[ni] = *(const bf16x8*)(Bs + (wc * 64 + ni * 16 + (l & 15)) * 64 + ks * 32 + (l >> 4) * 8);
            #pragma unroll
            for (int mi = 0; mi < 4; ++mi)
                #pragma unroll
                for (int ni = 0; ni < 4; ++ni)
                    acc[mi][ni] = __builtin_amdgcn_mfma_f32_16x16x32_bf16(a[mi], bfr[ni], acc[mi][ni], 0, 0, 0);
        }
        __syncthreads();
    }

    const float* bias = (p == 0) ? bq : (p == 1) ? bk : bv;
    if (p < 2) {
        unsigned short* O = (p == 0) ? Qh : Kh;
        #pragma unroll
        for (int ni = 0; ni < 4; ++ni) {
            int col = wc * 64 + ni * 16 + (l & 15);
            float bb = bias[col];
            #pragma unroll
            for (int mi = 0; mi < 4; ++mi) {
                int rbase = row0 + wr * 64 + mi * 16 + (l >> 4) * 4;
                #pragma unroll
                for (int r = 0; r < 4; ++r)
                    O[(size_t)(rbase + r) * H + col] = f2bf(acc[mi][ni][r] + bb);
            }
        }
    } else {
        int bidx = row0 >> 11;          // batch
        int tbase0 = row0 & (T - 1);    // token within batch
        #pragma unroll
        for (int ni = 0; ni < 4; ++ni) {
            int col = wc * 64 + ni * 16 + (l & 15);   // h
            float bb = bias[col];
            #pragma unroll
            for (int mi = 0; mi < 4; ++mi) {
                int t0 = tbase0 + wr * 64 + mi * 16 + (l >> 4) * 4;
                u16x4 u;
                #pragma unroll
                for (int r = 0; r < 4; ++r) u[r] = f2bf(acc[mi][ni][r] + bb);
                *(u16x4*)(Vt + ((size_t)bidx * H + col) * T + t0) = u;
            }
        }
    }
}

// ---------------------------------------------------------------------------
// K2: column-softmax stats (softmax over QUERY axis).
// NEW: 1D grid 512, balanced pairing (blocks c and c+256 complementary),
// double-buffered Q staging with early global-load issue (T14/G15).
// Block: 64 columns j; wave w owns 16 cols. K-frags register-resident.
// ---------------------------------------------------------------------------
__global__ __launch_bounds__(256) void colstats_kernel(
    const unsigned short* __restrict__ Qh, const unsigned short* __restrict__ Kh,
    float* __restrict__ cmax, float* __restrict__ cinv)
{
    const int tid = threadIdx.x;
    const int bid = blockIdx.x;            // 0..511
    const int hlf = bid >> 8, rr = bid & 255;
    const int b = rr >> 4, t = rr & 15;
    // work(tile) = 32 - tile; pair (31-t, t): works (t+1) + (32-t) = 33
    const int tile = hlf ? t : (31 - t);
    const int j0 = tile * 64;
    const int nt = 32 - tile;              // i-tiles from j0 to T

    const int l = tid & 63, w = tid >> 6;
    const unsigned short* Qb = Qh + (size_t)b * T * H;
    const unsigned short* Kb = Kh + (size_t)b * T * H;

    const int jc = j0 + w * 16 + (l & 15);   // this lane's column

    bf16x8 kf[4];
    #pragma unroll
    for (int ks = 0; ks < 4; ++ks)
        kf[ks] = *(const bf16x8*)(Kb + (size_t)jc * H + ks * 32 + (l >> 4) * 8);

    __shared__ __align__(16) unsigned short Qs[2][64 * 128];
    char* qs0 = (char*)Qs;

    u16x8 qreg[4];
    // prologue: load + write tile 0 (i0 = j0)
    #pragma unroll
    for (int c = 0; c < 4; ++c) {
        int idx = tid + c * 256;
        int row = idx >> 4, seg = idx & 15;
        qreg[c] = *(const u16x8*)(Qb + (size_t)(j0 + row) * H + seg * 8);
    }
    #pragma unroll
    for (int c = 0; c < 4; ++c) {
        int idx = tid + c * 256;
        int row = idx >> 4, seg = idx & 15;
        *(u16x8*)(qs0 + row * 256 + ((seg * 16) ^ ((row & 7) << 4))) = qreg[c];
    }
    __syncthreads();

    float m = -3.0e38f, s = 0.f;

    for (int it = 0; it < nt; ++it) {
        const int i0 = j0 + it * 64;
        char* qsb = qs0 + (it & 1) * 16384;
        // 1. early-issue next tile's global loads (results used after barrier)
        if (it + 1 < nt) {
            #pragma unroll
            for (int c = 0; c < 4; ++c) {
                int idx = tid + c * 256;
                int row = idx >> 4, seg = idx & 15;
                qreg[c] = *(const u16x8*)(Qb + (size_t)(i0 + 64 + row) * H + seg * 8);
            }
        }
        // 2. compute on current buffer
        float mv[16];
        #pragma unroll
        for (int mi = 0; mi < 4; ++mi) {
            f32x4 Dd = {0.f, 0.f, 0.f, 0.f};
            #pragma unroll
            for (int ks = 0; ks < 4; ++ks) {
                int row = mi * 16 + (l & 15);
                bf16x8 a = *(const bf16x8*)(qsb + row * 256 +
                            ((ks * 64 + (l >> 4) * 16) ^ ((l & 7) << 4)));
                Dd = __builtin_amdgcn_mfma_f32_16x16x32_bf16(a, kf[ks], Dd, 0, 0, 0);
            }
            #pragma unroll
            for (int r = 0; r < 4; ++r) {
                int i = i0 + mi * 16 + (l >> 4) * 4 + r;
                mv[mi * 4 + r] = (i >= jc) ? Dd[r] * SCALE : -3.0e38f;
            }
        }
        float tmax = mv[0];
        #pragma unroll
        for (int e = 1; e < 16; ++e) tmax = fmaxf(tmax, mv[e]);
        tmax = fmaxf(tmax, __shfl_xor(tmax, 16));
        tmax = fmaxf(tmax, __shfl_xor(tmax, 32));
        float newm = fmaxf(m, tmax);
        float tsum = 0.f;
        #pragma unroll
        for (int e = 0; e < 16; ++e)
            tsum += (mv[e] > -1.0e37f) ? __expf(mv[e] - newm) : 0.f;
        tsum += __shfl_xor(tsum, 16);
        tsum += __shfl_xor(tsum, 32);
        s = s * __expf(m - newm) + tsum;
        m = newm;
        // 3. all reads of current buffer done
        __syncthreads();
        // 4. write next tile into the other buffer
        if (it + 1 < nt) {
            char* nb = qs0 + ((it + 1) & 1) * 16384;
            #pragma unroll
            for (int c = 0; c < 4; ++c) {
                int idx = tid + c * 256;
                int row = idx >> 4, seg = idx & 15;
                *(u16x8*)(nb + row * 256 + ((seg * 16) ^ ((row & 7) << 4))) = qreg[c];
            }
        }
        __syncthreads();
    }
    if (l < 16) {
        cmax[(size_t)b * T + j0 + w * 16 + l] = m;
        cinv[(size_t)b * T + j0 + w * 16 + l] = 1.0f / s;
    }
}

// ---------------------------------------------------------------------------
// K3: out[i][h] = sum_{j<=i} exp(S*scale - cmax[j])*cinv[j] * V[j][h].
// NEW: 1D grid 512, balanced pairing; double-buffered K/V staging with
// early-issue; middle "P visible" barrier removed (Ps is per-wave; same-wave
// DS ordering is guaranteed by C++ semantics). 2 barriers/iter (was 3).
// ---------------------------------------------------------------------------
__global__ __launch_bounds__(256) void out_kernel(
    const unsigned short* __restrict__ Qh, const unsigned short* __restrict__ Kh,
    const unsigned short* __restrict__ Vt,
    const float* __restrict__ cmax, const float* __restrict__ cinv,
    float* __restrict__ out)
{
    const int tid = threadIdx.x;
    const int bid = blockIdx.x;            // 0..511
    const int hlf = bid >> 8, rr = bid & 255;
    const int b = rr >> 4, t = rr & 15;
    // work(tile) = tile+1; pair (t, 31-t): works (t+1) + (32-t) = 33
    const int tile = hlf ? (31 - t) : t;
    const int i0 = tile * 64;
    const int nt = tile + 1;               // j-tiles 0..tile

    const int l = tid & 63, w = tid >> 6;

    const unsigned short* Qb = Qh + (size_t)b * T * H;
    const unsigned short* Kb = Kh + (size_t)b * T * H;
    const unsigned short* Vb = Vt + (size_t)b * H * T;

    const int irow = i0 + w * 16 + (l & 15);   // A-frag row (m = i)
    bf16x8 qf[4];
    #pragma unroll
    for (int ks = 0; ks < 4; ++ks)
        qf[ks] = *(const bf16x8*)(Qb + (size_t)irow * H + ks * 32 + (l >> 4) * 8);

    const int iD = i0 + w * 16 + (l >> 4) * 4; // D-frag row base (i)

    f32x4 acc[8];
    #pragma unroll
    for (int nh = 0; nh < 8; ++nh)
        #pragma unroll
        for (int r = 0; r < 4; ++r) acc[nh][r] = 0.f;

    __shared__ __align__(16) unsigned short Ks[2][64 * 128];
    __shared__ __align__(16) unsigned short Vs[2][128 * 64];
    __shared__ __align__(16) unsigned short Ps[4 * 16 * 64];
    char* ks0 = (char*)Ks;
    char* vs0 = (char*)Vs;
    char* psb = (char*)(Ps + (size_t)w * 16 * 64);

    u16x8 kreg[4], vreg[4];
    // prologue: load + write tile j1=0
    #pragma unroll
    for (int c = 0; c < 4; ++c) {
        int idx = tid + c * 256;
        int krow = idx >> 4, kseg = idx & 15;
        kreg[c] = *(const u16x8*)(Kb + (size_t)krow * H + kseg * 8);
        int vrow = idx >> 3, vseg = idx & 7;
        vreg[c] = *(const u16x8*)(Vb + (size_t)vrow * T + 0 + vseg * 8);
    }
    #pragma unroll
    for (int c = 0; c < 4; ++c) {
        int idx = tid + c * 256;
        int krow = idx >> 4, kseg = idx & 15;
        *(u16x8*)(ks0 + krow * 256 + ((kseg * 16) ^ ((krow & 7) << 4))) = kreg[c];
        int vrow = idx >> 3, vseg = idx & 7;
        *(u16x8*)(vs0 + vrow * 128 + ((vseg * 16) ^ ((vrow & 7) << 4))) = vreg[c];
    }
    __syncthreads();

    for (int jt = 0; jt < nt; ++jt) {
        const int j1 = jt * 64;
        char* ksb = ks0 + (jt & 1) * 16384;
        char* vsb = vs0 + (jt & 1) * 16384;

        // 1. early-issue next tile's global loads
        if (jt + 1 < nt) {
            #pragma unroll
            for (int c = 0; c < 4; ++c) {
                int idx = tid + c * 256;
                int krow = idx >> 4, kseg = idx & 15;
                kreg[c] = *(const u16x8*)(Kb + (size_t)(j1 + 64 + krow) * H + kseg * 8);
                int vrow = idx >> 3, vseg = idx & 7;
                vreg[c] = *(const u16x8*)(Vb + (size_t)vrow * T + j1 + 64 + vseg * 8);
            }
        }

        // 2. compute on current buffers
        #pragma unroll
        for (int nj = 0; nj < 4; ++nj) {
            f32x4 Dd = {0.f, 0.f, 0.f, 0.f};
            #pragma unroll
            for (int ks = 0; ks < 4; ++ks) {
                int row = nj * 16 + (l & 15);
                bf16x8 bk = *(const bf16x8*)(ksb + row * 256 +
                             ((ks * 64 + (l >> 4) * 16) ^ ((l & 7) << 4)));
                Dd = __builtin_amdgcn_mfma_f32_16x16x32_bf16(qf[ks], bk, Dd, 0, 0, 0);
            }
            int jc = j1 + nj * 16 + (l & 15);
            float cm = cmax[(size_t)b * T + jc];
            float ci = cinv[(size_t)b * T + jc];
            #pragma unroll
            for (int r = 0; r < 4; ++r) {
                int i = iD + r;
                float pv = (jc <= i) ? __expf(Dd[r] * SCALE - cm) * ci : 0.f;
                int prow = (l >> 4) * 4 + r;
                *(unsigned short*)(psb + prow * 128 +
                    (((nj * 16 + (l & 15)) * 2) ^ ((prow & 7) << 4))) = f2bf(pv);
            }
        }
        // per-wave Ps: same-wave DS write->read ordering, no barrier needed
        #pragma unroll
        for (int ks2 = 0; ks2 < 2; ++ks2) {
            int prow = l & 15;
            bf16x8 ap = *(const bf16x8*)(psb + prow * 128 +
                         ((ks2 * 64 + (l >> 4) * 16) ^ ((prow & 7) << 4)));
            #pragma unroll
            for (int nh = 0; nh < 8; ++nh) {
                int vrow = nh * 16 + (l & 15);
                bf16x8 bv_ = *(const bf16x8*)(vsb + vrow * 128 +
                              ((ks2 * 64 + (l >> 4) * 16) ^ ((l & 7) << 4)));
                acc[nh] = __builtin_amdgcn_mfma_f32_16x16x32_bf16(ap, bv_, acc[nh], 0, 0, 0);
            }
        }
        // 3. all reads of current buffers done
        __syncthreads();
        // 4. write next tile into the other buffers
        if (jt + 1 < nt) {
            char* kn = ks0 + ((jt + 1) & 1) * 16384;
            char* vn = vs0 + ((jt + 1) & 1) * 16384;
            #pragma unroll
            for (int c = 0; c < 4; ++c) {
                int idx = tid + c * 256;
                int krow = idx >> 4, kseg = idx & 15;
                *(u16x8*)(kn + krow * 256 + ((kseg * 16) ^ ((krow & 7) << 4))) = kreg[c];
                int vrow = idx >> 3, vseg = idx & 7;
                *(u16x8*)(vn + vrow * 128 + ((vseg * 16) ^ ((vrow & 7) << 4))) = vreg[c];
            }
        }
        __syncthreads();
    }

    float* Ob = out + (size_t)b * T * H;
    #pragma unroll
    for (int nh = 0; nh < 8; ++nh) {
        int col = nh * 16 + (l & 15);
        #pragma unroll
        for (int r = 0; r < 4; ++r)
            Ob[(size_t)(iD + r) * H + col] = acc[nh][r];
    }
}

// ---------------------------------------------------------------------------
extern "C" void kernel_launch(void* const* d_in, const int* in_sizes, int n_in,
                              void* d_out, int out_size, void* d_ws, size_t ws_size,
                              hipStream_t stream)
{
    // inputs: x, Wk, bk, Wq, bq, Wv, bv (fp32)
    const float* x  = (const float*)d_in[0];
    const float* Wk = (const float*)d_in[1];
    const float* bk = (const float*)d_in[2];
    const float* Wq = (const float*)d_in[3];
    const float* bq = (const float*)d_in[4];
    const float* Wv = (const float*)d_in[5];
    const float* bv = (const float*)d_in[6];
    float* out = (float*)d_out;

    // ws layout (bytes): Qh 8M | Kh 8M | Vt 8M | Wt 768K | cmax 128K | cinv 128K
    char* ws = (char*)d_ws;
    unsigned short* Qh = (unsigned short*)(ws);
    unsigned short* Kh = (unsigned short*)(ws + 8388608);
    unsigned short* Vt = (unsigned short*)(ws + 16777216);
    unsigned short* Wt = (unsigned short*)(ws + 25165824);
    float* cmax = (float*)(ws + 25952256);
    float* cinv = (float*)(ws + 26083328);

    wt_kernel<<<dim3(32, 3), 256, 0, stream>>>(Wq, Wk, Wv, Wt);
    qkv_kernel<<<dim3(256, 3), 256, 0, stream>>>(x, Wt, bq, bk, bv, Qh, Kh, Vt);
    colstats_kernel<<<512, 256, 0, stream>>>(Qh, Kh, cmax, cinv);
    out_kernel<<<512, 256, 0, stream>>>(Qh, Kh, Vt, cmax, cinv, out);
}